// Round 6
// baseline (789.237 us; speedup 1.0000x reference)
//
#include <hip/hip_runtime.h>

// LightGNN: out = (x + c1 + c2 + c3)/4, x = emb[n_id], c_k = LGConv(c_{k-1})
// CSR-by-col + wave-per-node gather. y := cur*dinv stored bf16 (row = 32 u32).
// R6: MEASUREMENT ROUND. Real pipeline unchanged (355us baseline). Added
// probe_layer / probe_gather0: 12 internal reps of the hot-path workload so
// they exceed the ~143us top-5 cutoff and surface real counters.
// Probe cost is removed next round; per-phase cost = probe_dur/12.

#define D 64
#define REPS 12

typedef unsigned int u32;

__device__ inline float bf16lo(u32 u) { union { u32 i; float f; } c; c.i = u << 16; return c.f; }
__device__ inline float bf16hi(u32 u) { union { u32 i; float f; } c; c.i = u & 0xffff0000u; return c.f; }
__device__ inline u32 f2bf(float f) {
    union { float f; u32 i; } c; c.f = f;
    return (c.i + 0x7fffu + ((c.i >> 16) & 1u)) >> 16;
}
// opaque zero: defeats cross-rep CSE/LICM of global loads (compiler can't prove ==0)
__device__ __forceinline__ u32 opq0() { u32 z = 0; asm volatile("" : "+v"(z)); return z; }

// ---- zero fill ----
__global__ void zero_kernel(int4* __restrict__ p, int n4) {
    int i = blockIdx.x * blockDim.x + threadIdx.x;
    if (i < n4) p[i] = make_int4(0, 0, 0, 0);
}

// ---- degree histogram ----
__global__ void deg_kernel(const int* __restrict__ col, int* __restrict__ deg, int E) {
    int e = blockIdx.x * blockDim.x + threadIdx.x;
    if (e < E) atomicAdd(&deg[col[e]], 1);
}

__global__ void dinv_kernel(const int* __restrict__ deg, float* __restrict__ dinv, int N) {
    int i = blockIdx.x * blockDim.x + threadIdx.x;
    if (i < N) {
        int d = deg[i];
        dinv[i] = (d > 0) ? rsqrtf((float)d) : 0.0f;
    }
}

// ---- hierarchical exclusive scan ----
__global__ void scan1_kernel(const int* __restrict__ deg, int* __restrict__ part,
                             int* __restrict__ bsum, int N) {
    __shared__ int sm[256];
    int t = threadIdx.x;
    int base = blockIdx.x * 1024 + t * 4;
    int v[4]; int s = 0;
    for (int k = 0; k < 4; ++k) { int idx = base + k; v[k] = (idx < N) ? deg[idx] : 0; s += v[k]; }
    sm[t] = s; __syncthreads();
    for (int off = 1; off < 256; off <<= 1) {
        int x = (t >= off) ? sm[t - off] : 0;
        __syncthreads();
        sm[t] += x;
        __syncthreads();
    }
    int excl = sm[t] - s;
    if (t == 255) bsum[blockIdx.x] = sm[255];
    int run = excl;
    for (int k = 0; k < 4; ++k) { int idx = base + k; if (idx < N) part[idx] = run; run += v[k]; }
}

__global__ void scan2_kernel(int* __restrict__ bsum, int NB) {
    __shared__ int sm[256];
    int t = threadIdx.x;
    int v = (t < NB) ? bsum[t] : 0;
    sm[t] = v; __syncthreads();
    for (int off = 1; off < 256; off <<= 1) {
        int x = (t >= off) ? sm[t - off] : 0;
        __syncthreads();
        sm[t] += x;
        __syncthreads();
    }
    if (t < NB) bsum[t] = sm[t] - v;
}

__global__ void scan3_kernel(int* __restrict__ colptr, const int* __restrict__ bsum,
                             int* __restrict__ work, int N, int E) {
    int i = blockIdx.x * blockDim.x + threadIdx.x;
    if (i < N) {
        int v = colptr[i] + bsum[i >> 10];
        colptr[i] = v;
        work[i] = v;
    }
    if (i == 0) colptr[N] = E;
}

// ---- bucket scatter ----
__global__ void bucket_kernel(const int* __restrict__ row, const int* __restrict__ col,
                              int* __restrict__ work, int* __restrict__ rs, int E) {
    int e = blockIdx.x * blockDim.x + threadIdx.x;
    if (e < E) {
        int c = col[e];
        int p = atomicAdd(&work[c], 1);
        rs[p] = row[e];
    }
}

// ---- embedding gather ----
__global__ void gather0_kernel(const int* __restrict__ n_id, const float4* __restrict__ emb,
                               const float* __restrict__ dinv, uint2* __restrict__ y,
                               float4* __restrict__ out, int N) {
    int t = blockIdx.x * blockDim.x + threadIdx.x;
    if (t >= N * 16) return;
    int i = t >> 4, q = t & 15;
    float4 v = emb[(size_t)n_id[i] * 16 + q];
    float4 o; o.x = 0.25f * v.x; o.y = 0.25f * v.y; o.z = 0.25f * v.z; o.w = 0.25f * v.w;
    out[(size_t)i * 16 + q] = o;
    float di = dinv[i];
    uint2 p;
    p.x = f2bf(v.x * di) | (f2bf(v.y * di) << 16);
    p.y = f2bf(v.z * di) | (f2bf(v.w * di) << 16);
    y[(size_t)i * 16 + q] = p;
}

// ---- LGConv layer ----
template <bool WRITE_Y>
__global__ void layer_kernel(const int* __restrict__ colptr, const int* __restrict__ rs,
                             const float* __restrict__ dinv,
                             const u32* __restrict__ y,
                             u32* __restrict__ ynext,
                             float* __restrict__ out, int N) {
    int node = blockIdx.x * 4 + (threadIdx.x >> 6);
    if (node >= N) return;
    int lane = threadIdx.x & 63;
    int egrp = lane >> 3;
    int oct  = lane & 7;
    int s = colptr[node], e = colptr[node + 1];
    float a[8] = {0, 0, 0, 0, 0, 0, 0, 0};
    for (int i = s + egrp; i < e; i += 8) {
        int r = rs[i];
        uint4 w = *((const uint4*)(y + (size_t)r * 32) + oct);
        a[0] += bf16lo(w.x); a[1] += bf16hi(w.x);
        a[2] += bf16lo(w.y); a[3] += bf16hi(w.y);
        a[4] += bf16lo(w.z); a[5] += bf16hi(w.z);
        a[6] += bf16lo(w.w); a[7] += bf16hi(w.w);
    }
    #pragma unroll
    for (int m = 8; m <= 32; m <<= 1) {
        #pragma unroll
        for (int k = 0; k < 8; ++k) a[k] += __shfl_xor(a[k], m, 64);
    }
    if (lane < 8) {
        float di = dinv[node];
        float o[8];
        #pragma unroll
        for (int k = 0; k < 8; ++k) o[k] = a[k] * di;
        float4* op = (float4*)(out + (size_t)node * D) + oct * 2;
        float4 c0 = op[0], c1 = op[1];
        c0.x += 0.25f * o[0]; c0.y += 0.25f * o[1]; c0.z += 0.25f * o[2]; c0.w += 0.25f * o[3];
        c1.x += 0.25f * o[4]; c1.y += 0.25f * o[5]; c1.z += 0.25f * o[6]; c1.w += 0.25f * o[7];
        op[0] = c0; op[1] = c1;
        if (WRITE_Y) {
            uint4 w;
            w.x = f2bf(o[0] * di) | (f2bf(o[1] * di) << 16);
            w.y = f2bf(o[2] * di) | (f2bf(o[3] * di) << 16);
            w.z = f2bf(o[4] * di) | (f2bf(o[5] * di) << 16);
            w.w = f2bf(o[6] * di) | (f2bf(o[7] * di) << 16);
            *((uint4*)(ynext + (size_t)node * 32) + oct) = w;
        }
    }
}

// ---- PROBE: 12x layer workload in one dispatch (scratch-only writes) ----
__global__ void probe_layer(const int* __restrict__ colptr, const int* __restrict__ rs,
                            const float* __restrict__ dinv, const u32* __restrict__ y0,
                            u32* __restrict__ yP0, u32* __restrict__ yP1,
                            float* __restrict__ oP0, float* __restrict__ oP1, int N) {
    int node = blockIdx.x * 4 + (threadIdx.x >> 6);
    if (node >= N) return;
    int lane = threadIdx.x & 63;
    int egrp = lane >> 3;
    int oct  = lane & 7;
    int s = colptr[node], e = colptr[node + 1];
    for (int rep = 0; rep < REPS; ++rep) {
        const u32* y = y0 + opq0();               // opaque: forces fresh loads per rep
        float a[8] = {0, 0, 0, 0, 0, 0, 0, 0};
        for (int i = s + egrp; i < e; i += 8) {
            int r = rs[i + (int)opq0()];
            uint4 w = *((const uint4*)(y + (size_t)r * 32) + oct);
            a[0] += bf16lo(w.x); a[1] += bf16hi(w.x);
            a[2] += bf16lo(w.y); a[3] += bf16hi(w.y);
            a[4] += bf16lo(w.z); a[5] += bf16hi(w.z);
            a[6] += bf16lo(w.w); a[7] += bf16hi(w.w);
        }
        #pragma unroll
        for (int m = 8; m <= 32; m <<= 1) {
            #pragma unroll
            for (int k = 0; k < 8; ++k) a[k] += __shfl_xor(a[k], m, 64);
        }
        if (lane < 8) {
            float di = dinv[node];
            float o[8];
            #pragma unroll
            for (int k = 0; k < 8; ++k) o[k] = a[k] * di;
            float* ob = ((rep & 1) ? oP1 : oP0) + opq0();
            float4* op = (float4*)(ob + (size_t)node * D) + oct * 2;
            float4 c0 = op[0], c1 = op[1];
            c0.x += 0.25f * o[0]; c0.y += 0.25f * o[1]; c0.z += 0.25f * o[2]; c0.w += 0.25f * o[3];
            c1.x += 0.25f * o[4]; c1.y += 0.25f * o[5]; c1.z += 0.25f * o[6]; c1.w += 0.25f * o[7];
            op[0] = c0; op[1] = c1;
            u32* yb = ((rep & 1) ? yP1 : yP0) + opq0();
            uint4 w;
            w.x = f2bf(o[0] * di) | (f2bf(o[1] * di) << 16);
            w.y = f2bf(o[2] * di) | (f2bf(o[3] * di) << 16);
            w.z = f2bf(o[4] * di) | (f2bf(o[5] * di) << 16);
            w.w = f2bf(o[6] * di) | (f2bf(o[7] * di) << 16);
            *((uint4*)(yb + (size_t)node * 32) + oct) = w;
        }
    }
}

// ---- PROBE: 12x embedding-gather workload (scratch-only writes) ----
__global__ void probe_gather0(const int* __restrict__ n_id, const float4* __restrict__ emb,
                              const float* __restrict__ dinv,
                              uint2* __restrict__ yG0, uint2* __restrict__ yG1,
                              float4* __restrict__ oG0, float4* __restrict__ oG1, int N) {
    int t = blockIdx.x * blockDim.x + threadIdx.x;
    if (t >= N * 16) return;
    int i = t >> 4, q = t & 15;
    int nid = n_id[i];
    float di = dinv[i];
    for (int rep = 0; rep < REPS; ++rep) {
        const float4* e = emb + opq0();
        float4 v = e[(size_t)nid * 16 + q];
        float4 o; o.x = 0.25f * v.x; o.y = 0.25f * v.y; o.z = 0.25f * v.z; o.w = 0.25f * v.w;
        float4* og = ((rep & 1) ? oG1 : oG0) + opq0();
        og[(size_t)i * 16 + q] = o;
        uint2 p;
        p.x = f2bf(v.x * di) | (f2bf(v.y * di) << 16);
        p.y = f2bf(v.z * di) | (f2bf(v.w * di) << 16);
        uint2* yg = ((rep & 1) ? yG1 : yG0) + opq0();
        yg[(size_t)i * 16 + q] = p;
    }
}

extern "C" void kernel_launch(void* const* d_in, const int* in_sizes, int n_in,
                              void* d_out, int out_size, void* d_ws, size_t ws_size,
                              hipStream_t stream) {
    const int*    n_id = (const int*)d_in[0];
    const int*    edge = (const int*)d_in[1];
    const float*  emb  = (const float*)d_in[3];
    float* out = (float*)d_out;

    const int N = in_sizes[0];
    const int E = in_sizes[1] / 2;
    const int* row = edge;
    const int* col = edge + E;

    char* p = (char*)d_ws;
    auto alloc = [&](size_t bytes) { char* r = p; p += (bytes + 255) & ~(size_t)255; return r; };
    int*   deg    = (int*)  alloc((size_t)N * 4);
    float* dinv   = (float*)alloc((size_t)N * 4);
    int*   colptr = (int*)  alloc((size_t)(N + 1) * 4);
    int*   work   = (int*)  alloc((size_t)N * 4);
    int*   bsum   = (int*)  alloc(1024 * 4);
    int*   rs     = (int*)  alloc((size_t)E * 4);
    u32*   yA     = (u32*)  alloc((size_t)N * D * 2);
    u32*   yB     = (u32*)  alloc((size_t)N * D * 2);
    // probe scratch (alternating pairs to block DSE without blowing ws)
    u32*   yP0    = (u32*)  alloc((size_t)N * D * 2);
    u32*   yP1    = (u32*)  alloc((size_t)N * D * 2);
    float* oP0    = (float*)alloc((size_t)N * D * 4);
    float* oP1    = (float*)alloc((size_t)N * D * 4);
    uint2* yG0    = (uint2*)alloc((size_t)N * 16 * 8);
    uint2* yG1    = (uint2*)alloc((size_t)N * 16 * 8);
    float4* oG0   = (float4*)alloc((size_t)N * 16 * 16);
    float4* oG1   = (float4*)alloc((size_t)N * 16 * 16);

    const int BS = 256;
    const int NB = (N + 1023) / 1024;

    int n4 = (N + 3) / 4;
    zero_kernel<<<(n4 + BS - 1) / BS, BS, 0, stream>>>((int4*)deg, n4);
    deg_kernel<<<(E + BS - 1) / BS, BS, 0, stream>>>(col, deg, E);
    dinv_kernel<<<(N + BS - 1) / BS, BS, 0, stream>>>(deg, dinv, N);

    scan1_kernel<<<NB, BS, 0, stream>>>(deg, colptr, bsum, N);
    scan2_kernel<<<1, BS, 0, stream>>>(bsum, NB);
    scan3_kernel<<<(N + BS - 1) / BS, BS, 0, stream>>>(colptr, bsum, work, N, E);

    bucket_kernel<<<(E + BS - 1) / BS, BS, 0, stream>>>(row, col, work, rs, E);

    gather0_kernel<<<((size_t)N * 16 + BS - 1) / BS, BS, 0, stream>>>(
        n_id, (const float4*)emb, dinv, (uint2*)yA, (float4*)out, N);

    const int LGRID = (N + 3) / 4;
    layer_kernel<true ><<<LGRID, BS, 0, stream>>>(colptr, rs, dinv, yA, yB, out, N);
    layer_kernel<true ><<<LGRID, BS, 0, stream>>>(colptr, rs, dinv, yB, yA, out, N);
    layer_kernel<false><<<LGRID, BS, 0, stream>>>(colptr, rs, dinv, yA, yB, out, N);

    // ---- probes (after real work; scratch-only; removed next round) ----
    probe_layer<<<LGRID, BS, 0, stream>>>(colptr, rs, dinv, yA, yP0, yP1, oP0, oP1, N);
    probe_gather0<<<((size_t)N * 16 + BS - 1) / BS, BS, 0, stream>>>(
        n_id, (const float4*)emb, dinv, yG0, yG1, oG0, oG1, N);
}

// Round 8
// 345.462 us; speedup vs baseline: 2.2846x; 2.2846x over previous
//
#include <hip/hip_runtime.h>
#include <hip/hip_fp16.h>

// LightGNN: out = (x + c1 + c2 + c3)/4, x = emb[n_id], c_k = LGConv(c_{k-1})
// CSR-by-col + wave-per-node gather. y := cur*dinv stored FP16 (row = 128 B).
// R7: layer was VALU-bound (probe: 73% VALUBusy, 13.7% HBM). Switched y to
// fp16 + packed v_pk_add_f16 accumulation (no unpack in inner loop), packed
// shuffle reduce, byte-offset rs[], dinv fused into scan1.

#define D 64

typedef unsigned int u32;

__device__ inline __half2 u2h2(u32 u) { union { u32 i; __half2 h; } c; c.i = u; return c.h; }
__device__ inline u32 h22u(__half2 h) { union { u32 i; __half2 h; } c; c.h = h; return c.i; }

// ---- zero fill ----
__global__ void zero_kernel(int4* __restrict__ p, int n4) {
    int i = blockIdx.x * blockDim.x + threadIdx.x;
    if (i < n4) p[i] = make_int4(0, 0, 0, 0);
}

// ---- degree histogram ----
__global__ void deg_kernel(const int* __restrict__ col, int* __restrict__ deg, int E) {
    int e = blockIdx.x * blockDim.x + threadIdx.x;
    if (e < E) atomicAdd(&deg[col[e]], 1);
}

// ---- scan1 + fused dinv ----
__global__ void scan1_kernel(const int* __restrict__ deg, int* __restrict__ part,
                             int* __restrict__ bsum, float* __restrict__ dinv, int N) {
    __shared__ int sm[256];
    int t = threadIdx.x;
    int base = blockIdx.x * 1024 + t * 4;
    int v[4]; int s = 0;
    for (int k = 0; k < 4; ++k) {
        int idx = base + k;
        v[k] = (idx < N) ? deg[idx] : 0;
        s += v[k];
        if (idx < N) dinv[idx] = (v[k] > 0) ? rsqrtf((float)v[k]) : 0.0f;
    }
    sm[t] = s; __syncthreads();
    for (int off = 1; off < 256; off <<= 1) {
        int x = (t >= off) ? sm[t - off] : 0;
        __syncthreads();
        sm[t] += x;
        __syncthreads();
    }
    int excl = sm[t] - s;
    if (t == 255) bsum[blockIdx.x] = sm[255];
    int run = excl;
    for (int k = 0; k < 4; ++k) { int idx = base + k; if (idx < N) part[idx] = run; run += v[k]; }
}

__global__ void scan2_kernel(int* __restrict__ bsum, int NB) {
    __shared__ int sm[256];
    int t = threadIdx.x;
    int v = (t < NB) ? bsum[t] : 0;
    sm[t] = v; __syncthreads();
    for (int off = 1; off < 256; off <<= 1) {
        int x = (t >= off) ? sm[t - off] : 0;
        __syncthreads();
        sm[t] += x;
        __syncthreads();
    }
    if (t < NB) bsum[t] = sm[t] - v;
}

__global__ void scan3_kernel(int* __restrict__ colptr, const int* __restrict__ bsum,
                             int* __restrict__ work, int N, int E) {
    int i = blockIdx.x * blockDim.x + threadIdx.x;
    if (i < N) {
        int v = colptr[i] + bsum[i >> 10];
        colptr[i] = v;
        work[i] = v;
    }
    if (i == 0) colptr[N] = E;
}

// ---- bucket scatter: rs stores BYTE offset of source row (row*128) ----
__global__ void bucket_kernel(const int* __restrict__ row, const int* __restrict__ col,
                              int* __restrict__ work, int* __restrict__ rs, int E) {
    int e = blockIdx.x * blockDim.x + threadIdx.x;
    if (e < E) {
        int c = col[e];
        int p = atomicAdd(&work[c], 1);
        rs[p] = row[e] << 7;           // byte offset: row * D * sizeof(fp16) = row*128
    }
}

// ---- embedding gather: out = x/4 (fp32), y = x*dinv (fp16) ----
__global__ void gather0_kernel(const int* __restrict__ n_id, const float4* __restrict__ emb,
                               const float* __restrict__ dinv, uint2* __restrict__ y,
                               float4* __restrict__ out, int N) {
    int t = blockIdx.x * blockDim.x + threadIdx.x;
    if (t >= N * 16) return;
    int i = t >> 4, q = t & 15;
    float4 v = emb[(size_t)n_id[i] * 16 + q];
    float4 o; o.x = 0.25f * v.x; o.y = 0.25f * v.y; o.z = 0.25f * v.z; o.w = 0.25f * v.w;
    out[(size_t)i * 16 + q] = o;
    float di = dinv[i];
    uint2 p;
    p.x = h22u(__floats2half2_rn(v.x * di, v.y * di));
    p.y = h22u(__floats2half2_rn(v.z * di, v.w * di));
    y[(size_t)i * 16 + q] = p;
}

// ---- LGConv layer: wave = node; lane = (egrp l>>3, oct l&7) ----
// fp16 packed accumulate: 4 v_pk_add_f16 per 16 B; packed shuffle reduce.
template <bool WRITE_Y>
__global__ void layer_kernel(const int* __restrict__ colptr, const int* __restrict__ rs,
                             const float* __restrict__ dinv,
                             const char* __restrict__ y,      // row = 128 B fp16
                             char* __restrict__ ynext,
                             float* __restrict__ out, int N) {
    int node = blockIdx.x * 4 + (threadIdx.x >> 6);
    if (node >= N) return;
    int lane = threadIdx.x & 63;
    int egrp = lane >> 3;
    int octoff = (lane & 7) * 16;      // byte offset of this lane's 8 dims
    int s = colptr[node], e = colptr[node + 1];
    __half2 acc[4];
    acc[0] = acc[1] = acc[2] = acc[3] = __floats2half2_rn(0.0f, 0.0f);
    for (int i = s + egrp; i < e; i += 8) {
        int off = rs[i];
        uint4 w = *(const uint4*)(y + (size_t)off + octoff);
        acc[0] = __hadd2(acc[0], u2h2(w.x));
        acc[1] = __hadd2(acc[1], u2h2(w.y));
        acc[2] = __hadd2(acc[2], u2h2(w.z));
        acc[3] = __hadd2(acc[3], u2h2(w.w));
    }
    #pragma unroll
    for (int m = 8; m <= 32; m <<= 1) {
        #pragma unroll
        for (int k = 0; k < 4; ++k)
            acc[k] = __hadd2(acc[k], u2h2((u32)__shfl_xor((int)h22u(acc[k]), m, 64)));
    }
    if (lane < 8) {
        float di = dinv[node];
        float2 f0 = __half22float2(acc[0]);
        float2 f1 = __half22float2(acc[1]);
        float2 f2 = __half22float2(acc[2]);
        float2 f3 = __half22float2(acc[3]);
        float o[8] = { f0.x * di, f0.y * di, f1.x * di, f1.y * di,
                       f2.x * di, f2.y * di, f3.x * di, f3.y * di };
        float4* op = (float4*)(out + (size_t)node * D) + (octoff >> 3);
        float4 c0 = op[0], c1 = op[1];
        c0.x += 0.25f * o[0]; c0.y += 0.25f * o[1]; c0.z += 0.25f * o[2]; c0.w += 0.25f * o[3];
        c1.x += 0.25f * o[4]; c1.y += 0.25f * o[5]; c1.z += 0.25f * o[6]; c1.w += 0.25f * o[7];
        op[0] = c0; op[1] = c1;
        if (WRITE_Y) {
            uint4 w;
            w.x = h22u(__floats2half2_rn(o[0] * di, o[1] * di));
            w.y = h22u(__floats2half2_rn(o[2] * di, o[3] * di));
            w.z = h22u(__floats2half2_rn(o[4] * di, o[5] * di));
            w.w = h22u(__floats2half2_rn(o[6] * di, o[7] * di));
            *(uint4*)(ynext + (size_t)node * 128 + octoff) = w;
        }
    }
}

extern "C" void kernel_launch(void* const* d_in, const int* in_sizes, int n_in,
                              void* d_out, int out_size, void* d_ws, size_t ws_size,
                              hipStream_t stream) {
    const int*    n_id = (const int*)d_in[0];
    const int*    edge = (const int*)d_in[1];   // [2,E] flat
    const float*  emb  = (const float*)d_in[3];
    float* out = (float*)d_out;

    const int N = in_sizes[0];
    const int E = in_sizes[1] / 2;
    const int* row = edge;
    const int* col = edge + E;

    char* p = (char*)d_ws;
    auto alloc = [&](size_t bytes) { char* r = p; p += (bytes + 255) & ~(size_t)255; return r; };
    int*   deg    = (int*)  alloc((size_t)N * 4);
    float* dinv   = (float*)alloc((size_t)N * 4);
    int*   colptr = (int*)  alloc((size_t)(N + 1) * 4);
    int*   work   = (int*)  alloc((size_t)N * 4);
    int*   bsum   = (int*)  alloc(1024 * 4);
    int*   rs     = (int*)  alloc((size_t)E * 4);
    char*  yA     = (char*) alloc((size_t)N * D * 2);
    char*  yB     = (char*) alloc((size_t)N * D * 2);

    const int BS = 256;
    const int NB = (N + 1023) / 1024;

    int n4 = (N + 3) / 4;
    zero_kernel<<<(n4 + BS - 1) / BS, BS, 0, stream>>>((int4*)deg, n4);
    deg_kernel<<<(E + BS - 1) / BS, BS, 0, stream>>>(col, deg, E);

    scan1_kernel<<<NB, BS, 0, stream>>>(deg, colptr, bsum, dinv, N);
    scan2_kernel<<<1, BS, 0, stream>>>(bsum, NB);
    scan3_kernel<<<(N + BS - 1) / BS, BS, 0, stream>>>(colptr, bsum, work, N, E);

    bucket_kernel<<<(E + BS - 1) / BS, BS, 0, stream>>>(row, col, work, rs, E);

    gather0_kernel<<<((size_t)N * 16 + BS - 1) / BS, BS, 0, stream>>>(
        n_id, (const float4*)emb, dinv, (uint2*)yA, (float4*)out, N);

    const int LGRID = (N + 3) / 4;
    layer_kernel<true ><<<LGRID, BS, 0, stream>>>(colptr, rs, dinv, yA, yB, out, N);
    layer_kernel<true ><<<LGRID, BS, 0, stream>>>(colptr, rs, dinv, yB, yA, out, N);
    layer_kernel<false><<<LGRID, BS, 0, stream>>>(colptr, rs, dinv, yA, yB, out, N);
}